// Round 2
// baseline (390.877 us; speedup 1.0000x reference)
//
#include <hip/hip_runtime.h>
#include <stdint.h>
#include <stddef.h>

#define IN_F 4096
#define OUT_F 4096

typedef int i32x4 __attribute__((ext_vector_type(4)));

// ---------- helpers ----------

__device__ static inline void async16(const void* g, void* l) {
    __builtin_amdgcn_global_load_lds(
        (const __attribute__((address_space(1))) unsigned int*)g,
        (__attribute__((address_space(3))) unsigned int*)l,
        16, 0, 0);
}

__device__ static inline double wred_d(double v) {
#pragma unroll
    for (int o = 32; o > 0; o >>= 1) v += __shfl_down(v, o, 64);
    return v;
}

__device__ static inline int wred_i(int v) {
#pragma unroll
    for (int o = 32; o > 0; o >>= 1) v += __shfl_down(v, o, 64);
    return v;
}

__device__ static inline float wred_max(float v) {
#pragma unroll
    for (int o = 32; o > 0; o >>= 1) v = fmaxf(v, __shfl_down(v, o, 64));
    return v;
}

// ---------- K1: per-row stats only (register-resident, no T write) ----------
// one block per input row; thread owns 16 contiguous floats in VGPRs.

__global__ __launch_bounds__(256) void rowstats_kernel(
    const float* __restrict__ w,
    float* __restrict__ alpha_o,
    double* __restrict__ delta_o) {
    __shared__ double sh_s[4], sh_m[4];
    __shared__ int sh_c[4];
    const int row = blockIdx.x;
    const int t = threadIdx.x;
    const int lane = t & 63, wv = t >> 6;
    const float4* wr = (const float4*)(w + (size_t)row * OUT_F + t * 16);

    float4 v[4];
    double s = 0.0;
#pragma unroll
    for (int i = 0; i < 4; ++i) {
        v[i] = wr[i];
        s += (double)fabsf(v[i].x) + (double)fabsf(v[i].y) +
             (double)fabsf(v[i].z) + (double)fabsf(v[i].w);
    }
    double sw = wred_d(s);
    if (lane == 0) sh_s[wv] = sw;
    __syncthreads();
    const double delta = (sh_s[0] + sh_s[1] + sh_s[2] + sh_s[3]) *
                         (0.7 / (double)OUT_F);

    double ms = 0.0;
    int cnt = 0;
#pragma unroll
    for (int i = 0; i < 4; ++i) {
        float f[4] = {v[i].x, v[i].y, v[i].z, v[i].w};
#pragma unroll
        for (int j = 0; j < 4; ++j) {
            double a = (double)fabsf(f[j]);
            if (a > delta) { ms += a; ++cnt; }
        }
    }
    double msw = wred_d(ms);
    int cw = wred_i(cnt);
    if (lane == 0) { sh_m[wv] = msw; sh_c[wv] = cw; }
    __syncthreads();
    if (t == 0) {
        double mtot = sh_m[0] + sh_m[1] + sh_m[2] + sh_m[3];
        int ctot = sh_c[0] + sh_c[1] + sh_c[2] + sh_c[3];
        alpha_o[row] = (float)(mtot / (double)ctot);
        delta_o[row] = delta;
    }
}

// ---------- K2: fused ternarize + transpose  w[IN][OUT] -> Tt[OUT][IN] i8 ---
// 128x128 tile, 256 thr. In-register 4x4 byte-column packing -> dword LDS
// writes (row stride 33 dwords ~ conflict-light) -> uint4 coalesced stores.
// Eliminates the T intermediate entirely (saves 32 MB of HBM traffic).

__global__ __launch_bounds__(256) void tern_transpose_kernel(
    const float* __restrict__ w,
    const double* __restrict__ delta_i,
    int8_t* __restrict__ Tt) {
    __shared__ unsigned int ldsb[128 * 33];  // 16.9 KB
    const int t = threadIdx.x;
    const int i0 = blockIdx.y * 128;  // IN  (rows of w)
    const int j0 = blockIdx.x * 128;  // OUT (cols of w)

#pragma unroll
    for (int it = 0; it < 4; ++it) {
        int bb = it * 256 + t;
        int rg = bb >> 5;   // 0..31: group of 4 IN-rows
        int cc = bb & 31;   // 0..31: group of 4 OUT-cols (coalesced dim)
        unsigned int col[4] = {0u, 0u, 0u, 0u};
#pragma unroll
        for (int k = 0; k < 4; ++k) {
            int irow = i0 + rg * 4 + k;
            float4 v = *(const float4*)(w + (size_t)irow * OUT_F + j0 + cc * 4);
            double d = delta_i[irow];
            float f[4] = {v.x, v.y, v.z, v.w};
#pragma unroll
            for (int j = 0; j < 4; ++j) {
                int q = ((double)f[j] > d) ? 1 : (((double)f[j] < -d) ? -1 : 0);
                col[j] |= (unsigned int)(q & 0xff) << (k * 8);
            }
        }
#pragma unroll
        for (int j = 0; j < 4; ++j)
            ldsb[(cc * 4 + j) * 33 + rg] = col[j];
    }
    __syncthreads();
#pragma unroll
    for (int it = 0; it < 4; ++it) {
        int idx = it * 256 + t;
        int rr = idx >> 3;  // OUT-local row
        int c2 = idx & 7;   // 16B chunk along IN
        uint4 o;
        o.x = ldsb[rr * 33 + c2 * 4 + 0];
        o.y = ldsb[rr * 33 + c2 * 4 + 1];
        o.z = ldsb[rr * 33 + c2 * 4 + 2];
        o.w = ldsb[rr * 33 + c2 * 4 + 3];
        *(uint4*)(Tt + (size_t)(j0 + rr) * IN_F + i0 + c2 * 16) = o;
    }
}

// ---------- K3: per-batch-row quantize (register-resident, 16B stores) -----

__global__ __launch_bounds__(256) void xquant_kernel(
    const float* __restrict__ x,
    const float* __restrict__ alpha,
    int8_t* __restrict__ xq,
    float* __restrict__ scale_o) {
    __shared__ float sh_mx[4];
    const int row = blockIdx.x;
    const int t = threadIdx.x;
    const int lane = t & 63, wv = t >> 6;
    const float4* xr = (const float4*)(x + (size_t)row * IN_F + t * 16);
    const float4* ar = (const float4*)(alpha + t * 16);

    float4 xs[4];
    float mx = 0.0f;
#pragma unroll
    for (int i = 0; i < 4; ++i) {
        float4 v = xr[i];
        float4 a = ar[i];
        v.x *= a.x; v.y *= a.y; v.z *= a.z; v.w *= a.w;
        xs[i] = v;
        mx = fmaxf(mx, fmaxf(fmaxf(fabsf(v.x), fabsf(v.y)),
                             fmaxf(fabsf(v.z), fabsf(v.w))));
    }
    float mw = wred_max(mx);
    if (lane == 0) sh_mx[wv] = mw;
    __syncthreads();
    const float rmax = fmaxf(fmaxf(sh_mx[0], sh_mx[1]), fmaxf(sh_mx[2], sh_mx[3]));
    const float inv = (rmax > 0.0f) ? (127.0f / rmax) : 0.0f;

    uint4 o;
    unsigned int* op = (unsigned int*)&o;
#pragma unroll
    for (int i = 0; i < 4; ++i) {
        float f[4] = {xs[i].x, xs[i].y, xs[i].z, xs[i].w};
        unsigned int d = 0;
#pragma unroll
        for (int j = 0; j < 4; ++j) {
            int q = __float2int_rn(f[j] * inv);
            d |= (unsigned int)(q & 0xff) << (j * 8);
        }
        op[i] = d;
    }
    *(uint4*)(xq + (size_t)row * IN_F + t * 16) = o;
    if (t == 0) scale_o[row] = (rmax > 0.0f) ? (rmax / 127.0f) : 1.0f;
}

// ---------- K4: i8 MFMA GEMM, 256x256 8-phase, deepened prefetch -----------
// Stage slots reordered so every waited-on load is >=2 phases (~1300 cyc) old
// (> ~900 cyc HBM latency); vmcnt(4) at K-tile boundaries, 12 loads peak.

#define GBARRIER() asm volatile("s_barrier" ::: "memory")

#define STAGE(G, GR0, TILE, LBASE, HALF)                                        \
    do {                                                                        \
        _Pragma("unroll")                                                       \
        for (int rr_ = 0; rr_ < 2; ++rr_) {                                     \
            const int L_ = (HALF) * 1024 + rr_ * 512 + t;                       \
            const int row_ = L_ >> 3;                                           \
            const int gch_ = (L_ & 7) ^ (row_ & 7);                             \
            async16((G) + (size_t)((GR0) + row_) * IN_F + (TILE) * 128 +        \
                        (gch_ << 4),                                            \
                    (LBASE) + (L_ << 4));                                       \
        }                                                                       \
    } while (0)

#define READ_A(BUF, MI0)                                                        \
    _Pragma("unroll")                                                           \
    for (int mi_ = 0; mi_ < 4; ++mi_) {                                         \
        a[2 * mi_]     = *(const i32x4*)((BUF) + offA_k0 + ((MI0) + mi_) * 2048); \
        a[2 * mi_ + 1] = *(const i32x4*)((BUF) + offA_k1 + ((MI0) + mi_) * 2048); \
    }

#define READ_B(BUF, NI0, DST)                                                   \
    _Pragma("unroll")                                                           \
    for (int ni_ = 0; ni_ < 2; ++ni_) {                                         \
        DST[2 * ni_]     = *(const i32x4*)((BUF) + offB_k0 + ((NI0) + ni_) * 2048); \
        DST[2 * ni_ + 1] = *(const i32x4*)((BUF) + offB_k1 + ((NI0) + ni_) * 2048); \
    }

#define MFMA_Q(MI0, NI0, BSRC)                                                  \
    do {                                                                        \
        __builtin_amdgcn_s_setprio(1);                                          \
        _Pragma("unroll")                                                       \
        for (int mi_ = 0; mi_ < 4; ++mi_) {                                     \
            _Pragma("unroll")                                                   \
            for (int ni_ = 0; ni_ < 2; ++ni_) {                                 \
                acc[(MI0) + mi_][(NI0) + ni_] =                                 \
                    __builtin_amdgcn_mfma_i32_16x16x64_i8(                      \
                        a[2 * mi_], BSRC[2 * ni_],                              \
                        acc[(MI0) + mi_][(NI0) + ni_], 0, 0, 0);                \
                acc[(MI0) + mi_][(NI0) + ni_] =                                 \
                    __builtin_amdgcn_mfma_i32_16x16x64_i8(                      \
                        a[2 * mi_ + 1], BSRC[2 * ni_ + 1],                      \
                        acc[(MI0) + mi_][(NI0) + ni_], 0, 0, 0);                \
            }                                                                   \
        }                                                                       \
        __builtin_amdgcn_s_setprio(0);                                          \
    } while (0)

__global__ __launch_bounds__(512, 2) void gemm_i8_8ph(
    const int8_t* __restrict__ Xq,   // [M,K]
    const int8_t* __restrict__ Tq,   // [N,K]
    const float* __restrict__ scale, // [M]
    const float* __restrict__ bias,  // [N]
    float* __restrict__ out) {
    extern __shared__ __align__(16) int8_t lds[];  // 131072 B
    const int K = IN_F;
    const int NT = K / 128;   // 32 K-tiles
    const int NI = NT / 2;    // 16 iterations

    const int t = threadIdx.x;
    const int lane = t & 63;
    const int wave = t >> 6;
    const int lm = lane & 15;
    const int qh = lane >> 4;
    const int wm = (wave >> 2) << 7;
    const int wn = (wave & 3) << 6;

    const int nwg = gridDim.x;
    const int id = blockIdx.x;
    const int swz = (id & 7) * (nwg >> 3) + (id >> 3);
    const int m0 = (swz >> 4) << 8;
    const int n0 = (swz & 15) << 8;

    int8_t* const A0  = lds;
    int8_t* const B0  = lds + 32768;
    int8_t* const A1b = lds + 65536;
    int8_t* const B1b = lds + 98304;

    const int swzs = lm & 7;
    const int offA_k0 = (wm + lm) * 128 + ((qh ^ swzs) << 4);
    const int offA_k1 = (wm + lm) * 128 + (((4 + qh) ^ swzs) << 4);
    const int offB_k0 = (wn + lm) * 128 + ((qh ^ swzs) << 4);
    const int offB_k1 = (wn + lm) * 128 + (((4 + qh) ^ swzs) << 4);

    i32x4 acc[8][4];
#pragma unroll
    for (int i = 0; i < 8; ++i)
#pragma unroll
        for (int j = 0; j < 4; ++j)
#pragma unroll
            for (int r = 0; r < 4; ++r) acc[i][j][r] = 0;

    i32x4 a[8], bA[4], bB[4];

    // ---- prologue: tile0 fully + Blo(1), Alo(1); keep those 4 in flight
    STAGE(Xq, m0, 0, A0, 0);
    STAGE(Xq, m0, 0, A0, 1);
    STAGE(Tq, n0, 0, B0, 0);
    STAGE(Tq, n0, 0, B0, 1);
    STAGE(Tq, n0, 1, B1b, 0);
    STAGE(Xq, m0, 1, A1b, 0);
    asm volatile("s_waitcnt vmcnt(4)" ::: "memory");
    GBARRIER();

#pragma unroll 1
    for (int i = 0; i < NI; ++i) {
        const int kt = 2 * i;
        // -- phase 0: stage Bhi(kt+1)
        READ_A(A0, 0);
        READ_B(B0, 0, bA);
        STAGE(Tq, n0, kt + 1, B1b, 1);
        GBARRIER();
        MFMA_Q(0, 0, bA);
        GBARRIER();
        // -- phase 1: stage Ahi(kt+1)
        READ_B(B0, 2, bB);
        STAGE(Xq, m0, kt + 1, A1b, 1);
        GBARRIER();
        MFMA_Q(0, 2, bB);
        GBARRIER();
        // -- phase 2: stage Blo(kt+2)  (buf0 B free after ph1 reads)
        READ_A(A0, 4);
        if (kt + 2 < NT) STAGE(Tq, n0, kt + 2, B0, 0);
        GBARRIER();
        MFMA_Q(4, 0, bA);
        GBARRIER();
        // -- phase 3: stage Alo(kt+2); tile-boundary wait (>=2 phases old)
        if (kt + 2 < NT) STAGE(Xq, m0, kt + 2, A0, 0);
        GBARRIER();
        MFMA_Q(4, 2, bB);
        if (i + 1 < NI) asm volatile("s_waitcnt vmcnt(4)" ::: "memory");
        else            asm volatile("s_waitcnt vmcnt(0)" ::: "memory");
        GBARRIER();
        // -- phase 4: stage Bhi(kt+2)
        READ_A(A1b, 0);
        READ_B(B1b, 0, bA);
        if (kt + 2 < NT) STAGE(Tq, n0, kt + 2, B0, 1);
        GBARRIER();
        MFMA_Q(0, 0, bA);
        GBARRIER();
        // -- phase 5: stage Ahi(kt+2)
        READ_B(B1b, 2, bB);
        if (kt + 2 < NT) STAGE(Xq, m0, kt + 2, A0, 1);
        GBARRIER();
        MFMA_Q(0, 2, bB);
        GBARRIER();
        // -- phase 6: stage Blo(kt+3)  (buf1 B free after ph5 reads)
        READ_A(A1b, 4);
        if (kt + 3 < NT) STAGE(Tq, n0, kt + 3, B1b, 0);
        GBARRIER();
        MFMA_Q(4, 0, bA);
        GBARRIER();
        // -- phase 7: stage Alo(kt+3); tile-boundary wait
        if (kt + 3 < NT) STAGE(Xq, m0, kt + 3, A1b, 0);
        GBARRIER();
        MFMA_Q(4, 2, bB);
        if (i + 1 < NI) asm volatile("s_waitcnt vmcnt(4)" ::: "memory");
        GBARRIER();
    }

    // ---- epilogue
    const int q4 = qh << 2;
#pragma unroll
    for (int mi = 0; mi < 8; ++mi) {
        float sc[4];
#pragma unroll
        for (int r = 0; r < 4; ++r) sc[r] = scale[m0 + wm + mi * 16 + q4 + r];
#pragma unroll
        for (int ni = 0; ni < 4; ++ni) {
            int col = n0 + wn + ni * 16 + lm;
            float b = bias[col];
#pragma unroll
            for (int r = 0; r < 4; ++r) {
                int row = m0 + wm + mi * 16 + q4 + r;
                out[(size_t)row * OUT_F + col] =
                    (float)acc[mi][ni][r] * sc[r] + b;
            }
        }
    }
}

// ---------- launch ----------

extern "C" void kernel_launch(void* const* d_in, const int* in_sizes, int n_in,
                              void* d_out, int out_size, void* d_ws, size_t ws_size,
                              hipStream_t stream) {
    const float* x = (const float*)d_in[0];
    const float* w = (const float*)d_in[1];
    const float* bias = (const float*)d_in[2];
    float* out = (float*)d_out;
    const int B = in_sizes[0] / IN_F;  // 8192

    // ws layout (stays within proven 48M+48K bound):
    //   [0, 16M)        Tt [OUT][IN] i8
    //   [16M, 48M)      Xq [B][IN] i8
    //   [48M, 48M+16K)  alpha fp32[IN]
    //   [48M+16K, +32K) delta double[IN]  (K1->K2)  ALIASED with
    //                   scale fp32[B]     (K3->K4)  -- stream-serial safe:
    //                   K3 writes scale only after K2 finished reading delta.
    char* ws = (char*)d_ws;
    int8_t* Tt = (int8_t*)ws;
    int8_t* Xq = (int8_t*)(ws + (size_t)16777216);
    float* alpha = (float*)(ws + (size_t)50331648);
    double* delta = (double*)(ws + (size_t)50331648 + 16384);
    float* scale = (float*)(ws + (size_t)50331648 + 16384);

    static int lds_set = 0;
    if (!lds_set) {
        hipFuncSetAttribute((const void*)gemm_i8_8ph,
                            hipFuncAttributeMaxDynamicSharedMemorySize, 131072);
        lds_set = 1;
    }

    rowstats_kernel<<<IN_F, 256, 0, stream>>>(w, alpha, delta);
    tern_transpose_kernel<<<dim3(OUT_F / 128, IN_F / 128), 256, 0, stream>>>(w, delta, Tt);
    xquant_kernel<<<B, 256, 0, stream>>>(x, alpha, Xq, scale);
    const int nwg = (B / 256) * (OUT_F / 256);  // 512
    gemm_i8_8ph<<<dim3(nwg), dim3(512), 131072, stream>>>(Xq, Tt, scale, bias, out);
}

// Round 3
// 385.237 us; speedup vs baseline: 1.0146x; 1.0146x over previous
//
#include <hip/hip_runtime.h>
#include <stdint.h>
#include <stddef.h>

#define IN_F 4096
#define OUT_F 4096

typedef int i32x4 __attribute__((ext_vector_type(4)));

// ---------- helpers ----------

__device__ static inline void async16(const void* g, void* l) {
    __builtin_amdgcn_global_load_lds(
        (const __attribute__((address_space(1))) unsigned int*)g,
        (__attribute__((address_space(3))) unsigned int*)l,
        16, 0, 0);
}

__device__ static inline double wred_d(double v) {
#pragma unroll
    for (int o = 32; o > 0; o >>= 1) v += __shfl_down(v, o, 64);
    return v;
}

__device__ static inline int wred_i(int v) {
#pragma unroll
    for (int o = 32; o > 0; o >>= 1) v += __shfl_down(v, o, 64);
    return v;
}

__device__ static inline float wred_max(float v) {
#pragma unroll
    for (int o = 32; o > 0; o >>= 1) v = fmaxf(v, __shfl_down(v, o, 64));
    return v;
}

// ---------- K1: fused stats + packed ternarize -> T (dword-packed i8) ------
// one block per input row; lane-consecutive float4 loads (fully coalesced),
// register-resident, packed dword stores (no LDS roundtrip, no byte stores).

__global__ __launch_bounds__(256) void rowstats_tern_kernel(
    const float* __restrict__ w,
    float* __restrict__ alpha_o,
    unsigned int* __restrict__ Tp) {   // [IN][OUT/4] dwords
    __shared__ double sh_s[4], sh_m[4];
    __shared__ int sh_c[4];
    const int row = blockIdx.x;
    const int t = threadIdx.x;
    const int lane = t & 63, wv = t >> 6;
    const float4* wr = (const float4*)(w + (size_t)row * OUT_F);

    float4 v[4];
    double s = 0.0;
#pragma unroll
    for (int it = 0; it < 4; ++it) {
        v[it] = wr[t + it * 256];
        s += (double)fabsf(v[it].x) + (double)fabsf(v[it].y) +
             (double)fabsf(v[it].z) + (double)fabsf(v[it].w);
    }
    double sw = wred_d(s);
    if (lane == 0) sh_s[wv] = sw;
    __syncthreads();
    const double delta = (sh_s[0] + sh_s[1] + sh_s[2] + sh_s[3]) *
                         (0.7 / (double)OUT_F);

    unsigned int* trow = Tp + (size_t)row * (OUT_F / 4);
    double ms = 0.0;
    int cnt = 0;
#pragma unroll
    for (int it = 0; it < 4; ++it) {
        float f[4] = {v[it].x, v[it].y, v[it].z, v[it].w};
        unsigned int u = 0;
#pragma unroll
        for (int j = 0; j < 4; ++j) {
            double a = (double)fabsf(f[j]);
            if (a > delta) { ms += a; ++cnt; }
            int q = ((double)f[j] > delta) ? 1 :
                    (((double)f[j] < -delta) ? -1 : 0);
            u |= (unsigned int)(q & 0xff) << (j * 8);
        }
        trow[t + it * 256] = u;
    }
    double msw = wred_d(ms);
    int cw = wred_i(cnt);
    if (lane == 0) { sh_m[wv] = msw; sh_c[wv] = cw; }
    __syncthreads();
    if (t == 0) {
        double mtot = sh_m[0] + sh_m[1] + sh_m[2] + sh_m[3];
        int ctot = sh_c[0] + sh_c[1] + sh_c[2] + sh_c[3];
        alpha_o[row] = (float)(mtot / (double)ctot);
    }
}

// ---------- K2: byte transpose T[IN][OUT] -> Tt[OUT][IN] ----------
// 128x128 tile; dword loads (lane-consecutive), in-register 4x4 byte repack,
// dword LDS writes at stride-33, uint4 coalesced stores.

__global__ __launch_bounds__(256) void transpose_i8_kernel(
    const unsigned int* __restrict__ Tp,   // [IN][OUT/4]
    int8_t* __restrict__ Tt) {
    __shared__ unsigned int ldsb[128 * 33];  // 16.9 KB
    const int t = threadIdx.x;
    const int i0 = blockIdx.y * 128;  // IN
    const int j0 = blockIdx.x * 128;  // OUT

#pragma unroll
    for (int it = 0; it < 4; ++it) {
        int bb = it * 256 + t;
        int rg = bb >> 5;   // 0..31: group of 4 IN-rows
        int cc = bb & 31;   // 0..31: dword col (coalesced dim)
        unsigned int col[4] = {0u, 0u, 0u, 0u};
#pragma unroll
        for (int k = 0; k < 4; ++k) {
            unsigned int d = Tp[(size_t)(i0 + rg * 4 + k) * (OUT_F / 4) +
                                (j0 >> 2) + cc];
            col[0] |= (d & 0xffu) << (k * 8);
            col[1] |= ((d >> 8) & 0xffu) << (k * 8);
            col[2] |= ((d >> 16) & 0xffu) << (k * 8);
            col[3] |= ((d >> 24) & 0xffu) << (k * 8);
        }
#pragma unroll
        for (int j = 0; j < 4; ++j)
            ldsb[(cc * 4 + j) * 33 + rg] = col[j];
    }
    __syncthreads();
#pragma unroll
    for (int it = 0; it < 4; ++it) {
        int idx = it * 256 + t;
        int rr = idx >> 3;  // OUT-local row
        int c2 = idx & 7;   // 16B chunk along IN
        uint4 o;
        o.x = ldsb[rr * 33 + c2 * 4 + 0];
        o.y = ldsb[rr * 33 + c2 * 4 + 1];
        o.z = ldsb[rr * 33 + c2 * 4 + 2];
        o.w = ldsb[rr * 33 + c2 * 4 + 3];
        *(uint4*)(Tt + (size_t)(j0 + rr) * IN_F + i0 + c2 * 16) = o;
    }
}

// ---------- K3: per-batch-row quantize (coalesced, packed dword stores) ----

__global__ __launch_bounds__(256) void xquant_kernel(
    const float* __restrict__ x,
    const float* __restrict__ alpha,
    int8_t* __restrict__ xq,
    float* __restrict__ scale_o) {
    __shared__ float sh_mx[4];
    const int row = blockIdx.x;
    const int t = threadIdx.x;
    const int lane = t & 63, wv = t >> 6;
    const float4* xr = (const float4*)(x + (size_t)row * IN_F);
    const float4* ar = (const float4*)alpha;

    float4 xs[4];
    float mx = 0.0f;
#pragma unroll
    for (int it = 0; it < 4; ++it) {
        float4 v = xr[t + it * 256];
        float4 a = ar[t + it * 256];
        v.x *= a.x; v.y *= a.y; v.z *= a.z; v.w *= a.w;
        xs[it] = v;
        mx = fmaxf(mx, fmaxf(fmaxf(fabsf(v.x), fabsf(v.y)),
                             fmaxf(fabsf(v.z), fabsf(v.w))));
    }
    float mw = wred_max(mx);
    if (lane == 0) sh_mx[wv] = mw;
    __syncthreads();
    const float rmax = fmaxf(fmaxf(sh_mx[0], sh_mx[1]), fmaxf(sh_mx[2], sh_mx[3]));
    const float inv = (rmax > 0.0f) ? (127.0f / rmax) : 0.0f;

    unsigned int* qd = (unsigned int*)(xq + (size_t)row * IN_F);
#pragma unroll
    for (int it = 0; it < 4; ++it) {
        float f[4] = {xs[it].x, xs[it].y, xs[it].z, xs[it].w};
        unsigned int u = 0;
#pragma unroll
        for (int j = 0; j < 4; ++j) {
            int q = __float2int_rn(f[j] * inv);
            u |= (unsigned int)(q & 0xff) << (j * 8);
        }
        qd[t + it * 256] = u;
    }
    if (t == 0) scale_o[row] = (rmax > 0.0f) ? (rmax / 127.0f) : 1.0f;
}

// ---------- K4: i8 MFMA GEMM, 256x256, 4 long phases (32 MFMA each) --------
// Phase merge: per K-tile 2 phases of {reads; 2xSTAGE; bar; 32 MFMA; bar}.
// Counted vmcnt(4) at phase-1/3 ends only. Buffer lifetimes:
//   B0 free after ph0 -> staged ph1; A0 free after ph1 -> staged ph2;
//   B1 free after ph2 -> staged ph3; A1 free after ph3 -> staged next ph0.

#define GBARRIER() asm volatile("s_barrier" ::: "memory")

#define STAGE(G, GR0, TILE, LBASE, HALF)                                        \
    do {                                                                        \
        _Pragma("unroll")                                                       \
        for (int rr_ = 0; rr_ < 2; ++rr_) {                                     \
            const int L_ = (HALF) * 1024 + rr_ * 512 + t;                       \
            const int row_ = L_ >> 3;                                           \
            const int gch_ = (L_ & 7) ^ (row_ & 7);                             \
            async16((G) + (size_t)((GR0) + row_) * IN_F + (TILE) * 128 +        \
                        (gch_ << 4),                                            \
                    (LBASE) + (L_ << 4));                                       \
        }                                                                       \
    } while (0)

#define READ_A(BUF, MI0)                                                        \
    _Pragma("unroll")                                                           \
    for (int mi_ = 0; mi_ < 4; ++mi_) {                                         \
        a[2 * mi_]     = *(const i32x4*)((BUF) + offA_k0 + ((MI0) + mi_) * 2048); \
        a[2 * mi_ + 1] = *(const i32x4*)((BUF) + offA_k1 + ((MI0) + mi_) * 2048); \
    }

#define READ_B(BUF, NI0, DST)                                                   \
    _Pragma("unroll")                                                           \
    for (int ni_ = 0; ni_ < 2; ++ni_) {                                         \
        DST[2 * ni_]     = *(const i32x4*)((BUF) + offB_k0 + ((NI0) + ni_) * 2048); \
        DST[2 * ni_ + 1] = *(const i32x4*)((BUF) + offB_k1 + ((NI0) + ni_) * 2048); \
    }

#define MFMA_Q(MI0, NI0, BSRC)                                                  \
    do {                                                                        \
        __builtin_amdgcn_s_setprio(1);                                          \
        _Pragma("unroll")                                                       \
        for (int mi_ = 0; mi_ < 4; ++mi_) {                                     \
            _Pragma("unroll")                                                   \
            for (int ni_ = 0; ni_ < 2; ++ni_) {                                 \
                acc[(MI0) + mi_][(NI0) + ni_] =                                 \
                    __builtin_amdgcn_mfma_i32_16x16x64_i8(                      \
                        a[2 * mi_], BSRC[2 * ni_],                              \
                        acc[(MI0) + mi_][(NI0) + ni_], 0, 0, 0);                \
                acc[(MI0) + mi_][(NI0) + ni_] =                                 \
                    __builtin_amdgcn_mfma_i32_16x16x64_i8(                      \
                        a[2 * mi_ + 1], BSRC[2 * ni_ + 1],                      \
                        acc[(MI0) + mi_][(NI0) + ni_], 0, 0, 0);                \
            }                                                                   \
        }                                                                       \
        __builtin_amdgcn_s_setprio(0);                                          \
    } while (0)

__global__ __launch_bounds__(512, 2) void gemm_i8_8ph(
    const int8_t* __restrict__ Xq,   // [M,K]
    const int8_t* __restrict__ Tq,   // [N,K]
    const float* __restrict__ scale, // [M]
    const float* __restrict__ bias,  // [N]
    float* __restrict__ out) {
    extern __shared__ __align__(16) int8_t lds[];  // 131072 B
    const int K = IN_F;
    const int NT = K / 128;   // 32 K-tiles
    const int NI = NT / 2;    // 16 iterations

    const int t = threadIdx.x;
    const int lane = t & 63;
    const int wave = t >> 6;
    const int lm = lane & 15;
    const int qh = lane >> 4;
    const int wm = (wave >> 2) << 7;
    const int wn = (wave & 3) << 6;

    const int nwg = gridDim.x;
    const int id = blockIdx.x;
    const int swz = (id & 7) * (nwg >> 3) + (id >> 3);
    const int m0 = (swz >> 4) << 8;
    const int n0 = (swz & 15) << 8;

    int8_t* const A0  = lds;
    int8_t* const B0  = lds + 32768;
    int8_t* const A1b = lds + 65536;
    int8_t* const B1b = lds + 98304;

    const int swzs = lm & 7;
    const int offA_k0 = (wm + lm) * 128 + ((qh ^ swzs) << 4);
    const int offA_k1 = (wm + lm) * 128 + (((4 + qh) ^ swzs) << 4);
    const int offB_k0 = (wn + lm) * 128 + ((qh ^ swzs) << 4);
    const int offB_k1 = (wn + lm) * 128 + (((4 + qh) ^ swzs) << 4);

    i32x4 acc[8][4];
#pragma unroll
    for (int i = 0; i < 8; ++i)
#pragma unroll
        for (int j = 0; j < 4; ++j)
#pragma unroll
            for (int r = 0; r < 4; ++r) acc[i][j][r] = 0;

    i32x4 a[8], bA[4], bB[4];

    // ---- prologue: A(0),B(0)->buf0, B(1)->B1; leave B(1)'s 4 in flight
    STAGE(Xq, m0, 0, A0, 0);
    STAGE(Xq, m0, 0, A0, 1);
    STAGE(Tq, n0, 0, B0, 0);
    STAGE(Tq, n0, 0, B0, 1);
    STAGE(Tq, n0, 1, B1b, 0);
    STAGE(Tq, n0, 1, B1b, 1);
    asm volatile("s_waitcnt vmcnt(4)" ::: "memory");
    GBARRIER();

#pragma unroll 1
    for (int i = 0; i < NI; ++i) {
        const int kt = 2 * i;
        // -- phase 0: buf0 A-lo + B all; stage A(kt+1)->A1
        READ_A(A0, 0);
        READ_B(B0, 0, bA);
        READ_B(B0, 2, bB);
        STAGE(Xq, m0, kt + 1, A1b, 0);
        STAGE(Xq, m0, kt + 1, A1b, 1);
        GBARRIER();
        MFMA_Q(0, 0, bA);
        MFMA_Q(0, 2, bB);
        GBARRIER();
        // -- phase 1: buf0 A-hi; stage B(kt+2)->B0; wait A1,B1 ready
        READ_A(A0, 4);
        if (kt + 2 < NT) {
            STAGE(Tq, n0, kt + 2, B0, 0);
            STAGE(Tq, n0, kt + 2, B0, 1);
        }
        GBARRIER();
        MFMA_Q(4, 0, bA);
        MFMA_Q(4, 2, bB);
        asm volatile("s_waitcnt vmcnt(4)" ::: "memory");
        GBARRIER();
        // -- phase 2: buf1 A-lo + B all; stage A(kt+2)->A0
        READ_A(A1b, 0);
        READ_B(B1b, 0, bA);
        READ_B(B1b, 2, bB);
        if (kt + 2 < NT) {
            STAGE(Xq, m0, kt + 2, A0, 0);
            STAGE(Xq, m0, kt + 2, A0, 1);
        }
        GBARRIER();
        MFMA_Q(0, 0, bA);
        MFMA_Q(0, 2, bB);
        GBARRIER();
        // -- phase 3: buf1 A-hi; stage B(kt+3)->B1; wait A0,B0 ready
        READ_A(A1b, 4);
        if (kt + 3 < NT) {
            STAGE(Tq, n0, kt + 3, B1b, 0);
            STAGE(Tq, n0, kt + 3, B1b, 1);
        }
        GBARRIER();
        MFMA_Q(4, 0, bA);
        MFMA_Q(4, 2, bB);
        if (i + 1 < NI) asm volatile("s_waitcnt vmcnt(4)" ::: "memory");
        else            asm volatile("s_waitcnt vmcnt(0)" ::: "memory");
        GBARRIER();
    }

    // ---- epilogue
    const int q4 = qh << 2;
#pragma unroll
    for (int mi = 0; mi < 8; ++mi) {
        float sc[4];
#pragma unroll
        for (int r = 0; r < 4; ++r) sc[r] = scale[m0 + wm + mi * 16 + q4 + r];
#pragma unroll
        for (int ni = 0; ni < 4; ++ni) {
            int col = n0 + wn + ni * 16 + lm;
            float b = bias[col];
#pragma unroll
            for (int r = 0; r < 4; ++r) {
                int row = m0 + wm + mi * 16 + q4 + r;
                out[(size_t)row * OUT_F + col] =
                    (float)acc[mi][ni][r] * sc[r] + b;
            }
        }
    }
}

// ---------- launch ----------

extern "C" void kernel_launch(void* const* d_in, const int* in_sizes, int n_in,
                              void* d_out, int out_size, void* d_ws, size_t ws_size,
                              hipStream_t stream) {
    const float* x = (const float*)d_in[0];
    const float* w = (const float*)d_in[1];
    const float* bias = (const float*)d_in[2];
    float* out = (float*)d_out;
    const int B = in_sizes[0] / IN_F;  // 8192

    // ws layout (48M + 48K):
    //   [0, 16M)        Tt [OUT][IN] i8
    //   [16M, 32M)      Tp [IN][OUT] packed i8 (K1->K2 temp)   ALIASED with
    //   [16M, 48M)      Xq [B][IN] i8 (K3 writes after K2 read Tp; serial-safe)
    //   [48M, 48M+16K)  alpha fp32[IN]
    //   [48M+16K, ..)   scale fp32[B]
    char* ws = (char*)d_ws;
    int8_t* Tt = (int8_t*)ws;
    unsigned int* Tp = (unsigned int*)(ws + (size_t)16777216);
    int8_t* Xq = (int8_t*)(ws + (size_t)16777216);
    float* alpha = (float*)(ws + (size_t)50331648);
    float* scale = (float*)(ws + (size_t)50331648 + 16384);

    static int lds_set = 0;
    if (!lds_set) {
        hipFuncSetAttribute((const void*)gemm_i8_8ph,
                            hipFuncAttributeMaxDynamicSharedMemorySize, 131072);
        lds_set = 1;
    }

    rowstats_tern_kernel<<<IN_F, 256, 0, stream>>>(w, alpha, Tp);
    transpose_i8_kernel<<<dim3(OUT_F / 128, IN_F / 128), 256, 0, stream>>>(Tp, Tt);
    xquant_kernel<<<B, 256, 0, stream>>>(x, alpha, Xq, scale);
    const int nwg = (B / 256) * (OUT_F / 256);  // 512
    gemm_i8_8ph<<<dim3(nwg), dim3(512), 131072, stream>>>(Xq, Tt, scale, bias, out);
}

// Round 6
// 376.958 us; speedup vs baseline: 1.0369x; 1.0220x over previous
//
#include <hip/hip_runtime.h>
#include <stdint.h>
#include <stddef.h>

#define IN_F 4096
#define OUT_F 4096

typedef int i32x4 __attribute__((ext_vector_type(4)));

// small cross-dispatch buffers live in device globals (no ws aliasing games)
__device__ float  g_alpha[IN_F];
__device__ double g_delta[IN_F];
__device__ float  g_scale[8192];

// ---------- helpers ----------

__device__ static inline void async16(const void* g, void* l) {
    __builtin_amdgcn_global_load_lds(
        (const __attribute__((address_space(1))) unsigned int*)g,
        (__attribute__((address_space(3))) unsigned int*)l,
        16, 0, 0);
}

__device__ static inline double wred_d(double v) {
#pragma unroll
    for (int o = 32; o > 0; o >>= 1) v += __shfl_down(v, o, 64);
    return v;
}

__device__ static inline int wred_i(int v) {
#pragma unroll
    for (int o = 32; o > 0; o >>= 1) v += __shfl_down(v, o, 64);
    return v;
}

__device__ static inline float wred_max(float v) {
#pragma unroll
    for (int o = 32; o > 0; o >>= 1) v = fmaxf(v, __shfl_down(v, o, 64));
    return v;
}

// ---------- D1: per-row stats only -> g_alpha, g_delta ----------
// one block per input row; lane-consecutive float4 loads; register-resident.

__global__ __launch_bounds__(256) void rowstats_kernel(
    const float* __restrict__ w) {
    __shared__ double sh_s[4], sh_m[4];
    __shared__ int sh_c[4];
    const int row = blockIdx.x;
    const int t = threadIdx.x;
    const int lane = t & 63, wv = t >> 6;
    const float4* wr = (const float4*)(w + (size_t)row * OUT_F);

    float4 v[4];
    double s = 0.0;
#pragma unroll
    for (int it = 0; it < 4; ++it) {
        v[it] = wr[t + it * 256];
        s += (double)fabsf(v[it].x) + (double)fabsf(v[it].y) +
             (double)fabsf(v[it].z) + (double)fabsf(v[it].w);
    }
    double sw = wred_d(s);
    if (lane == 0) sh_s[wv] = sw;
    __syncthreads();
    const double delta = (sh_s[0] + sh_s[1] + sh_s[2] + sh_s[3]) *
                         (0.7 / (double)OUT_F);

    double ms = 0.0;
    int cnt = 0;
#pragma unroll
    for (int it = 0; it < 4; ++it) {
        float f[4] = {v[it].x, v[it].y, v[it].z, v[it].w};
#pragma unroll
        for (int j = 0; j < 4; ++j) {
            double a = (double)fabsf(f[j]);
            if (a > delta) { ms += a; ++cnt; }
        }
    }
    double msw = wred_d(ms);
    int cw = wred_i(cnt);
    if (lane == 0) { sh_m[wv] = msw; sh_c[wv] = cw; }
    __syncthreads();
    if (t == 0) {
        double mtot = sh_m[0] + sh_m[1] + sh_m[2] + sh_m[3];
        int ctot = sh_c[0] + sh_c[1] + sh_c[2] + sh_c[3];
        g_alpha[row] = (float)(mtot / (double)ctot);
        g_delta[row] = delta;
    }
}

// ---------- D2: fused {xquant | tern+transpose} in one dispatch ----------
// blocks [0,nxq): xquant (R3-verified math); blocks [nxq, nxq+1024):
// ternarize+transpose reading w directly (R2-verified math). The two halves
// are data-independent -> no intra-dispatch ordering required.

__global__ __launch_bounds__(256) void fused_tq(
    const float* __restrict__ w,
    const float* __restrict__ x,
    int8_t* __restrict__ Xq,
    int8_t* __restrict__ Tt,
    int nxq) {
    __shared__ __align__(16) unsigned int ldsb[128 * 33];  // 16.9 KB
    const int t = threadIdx.x;

    if ((int)blockIdx.x < nxq) {
        // ---- xquant: one batch row per block ----
        float* sh_mx = (float*)ldsb;
        const int row = blockIdx.x;
        const int lane = t & 63, wv = t >> 6;
        const float4* xr = (const float4*)(x + (size_t)row * IN_F);
        const float4* ar = (const float4*)g_alpha;

        float4 xs[4];
        float mx = 0.0f;
#pragma unroll
        for (int it = 0; it < 4; ++it) {
            float4 v = xr[t + it * 256];
            float4 a = ar[t + it * 256];
            v.x *= a.x; v.y *= a.y; v.z *= a.z; v.w *= a.w;
            xs[it] = v;
            mx = fmaxf(mx, fmaxf(fmaxf(fabsf(v.x), fabsf(v.y)),
                                 fmaxf(fabsf(v.z), fabsf(v.w))));
        }
        float mw = wred_max(mx);
        if (lane == 0) sh_mx[wv] = mw;
        __syncthreads();
        const float rmax = fmaxf(fmaxf(sh_mx[0], sh_mx[1]),
                                 fmaxf(sh_mx[2], sh_mx[3]));
        const float inv = (rmax > 0.0f) ? (127.0f / rmax) : 0.0f;

        unsigned int* qd = (unsigned int*)(Xq + (size_t)row * IN_F);
#pragma unroll
        for (int it = 0; it < 4; ++it) {
            float f[4] = {xs[it].x, xs[it].y, xs[it].z, xs[it].w};
            unsigned int u = 0;
#pragma unroll
            for (int j = 0; j < 4; ++j) {
                int q = __float2int_rn(f[j] * inv);
                u |= (unsigned int)(q & 0xff) << (j * 8);
            }
            qd[t + it * 256] = u;
        }
        if (t == 0) g_scale[row] = (rmax > 0.0f) ? (rmax / 127.0f) : 1.0f;
    } else {
        // ---- ternarize + transpose one 128x128 tile ----
        const int tt = blockIdx.x - nxq;
        const int i0 = (tt >> 5) * 128;  // IN
        const int j0 = (tt & 31) * 128;  // OUT
#pragma unroll
        for (int it = 0; it < 4; ++it) {
            int bb = it * 256 + t;
            int rg = bb >> 5;   // group of 4 IN-rows
            int cc = bb & 31;   // group of 4 OUT-cols (coalesced dim)
            unsigned int col[4] = {0u, 0u, 0u, 0u};
#pragma unroll
            for (int k = 0; k < 4; ++k) {
                int irow = i0 + rg * 4 + k;
                float4 v = *(const float4*)(w + (size_t)irow * OUT_F + j0 + cc * 4);
                double d = g_delta[irow];
                float f[4] = {v.x, v.y, v.z, v.w};
#pragma unroll
                for (int j = 0; j < 4; ++j) {
                    int q = ((double)f[j] > d) ? 1 : (((double)f[j] < -d) ? -1 : 0);
                    col[j] |= (unsigned int)(q & 0xff) << (k * 8);
                }
            }
#pragma unroll
            for (int j = 0; j < 4; ++j)
                ldsb[(cc * 4 + j) * 33 + rg] = col[j];
        }
        __syncthreads();
#pragma unroll
        for (int it = 0; it < 4; ++it) {
            int idx = it * 256 + t;
            int rr = idx >> 3;  // OUT-local row
            int c2 = idx & 7;   // 16B chunk along IN
            uint4 o;
            o.x = ldsb[rr * 33 + c2 * 4 + 0];
            o.y = ldsb[rr * 33 + c2 * 4 + 1];
            o.z = ldsb[rr * 33 + c2 * 4 + 2];
            o.w = ldsb[rr * 33 + c2 * 4 + 3];
            *(uint4*)(Tt + (size_t)(j0 + rr) * IN_F + i0 + c2 * 16) = o;
        }
    }
}

// ---------- D3: i8 MFMA GEMM, 256x256, 4 phases, ONE barrier per phase -----
// WAR safety: a wave reaching the end-of-phase barrier has drained its
// ds_reads (consumed by MFMA via compiler lgkmcnt); stages targeting a
// buffer last read in phase p are issued after p's end barrier.
// RAW safety: counted vmcnt before the barrier preceding the buffer's reads.
// Last iteration waits vmcnt(0) (no new stages in flight).

#define GBARRIER() asm volatile("s_barrier" ::: "memory")

#define STAGE(G, GR0, TILE, LBASE, HALF)                                        \
    do {                                                                        \
        _Pragma("unroll")                                                       \
        for (int rr_ = 0; rr_ < 2; ++rr_) {                                     \
            const int L_ = (HALF) * 1024 + rr_ * 512 + t;                       \
            const int row_ = L_ >> 3;                                           \
            const int gch_ = (L_ & 7) ^ (row_ & 7);                             \
            async16((G) + (size_t)((GR0) + row_) * IN_F + (TILE) * 128 +        \
                        (gch_ << 4),                                            \
                    (LBASE) + (L_ << 4));                                       \
        }                                                                       \
    } while (0)

#define READ_A(BUF, MI0)                                                        \
    _Pragma("unroll")                                                           \
    for (int mi_ = 0; mi_ < 4; ++mi_) {                                         \
        a[2 * mi_]     = *(const i32x4*)((BUF) + offA_k0 + ((MI0) + mi_) * 2048); \
        a[2 * mi_ + 1] = *(const i32x4*)((BUF) + offA_k1 + ((MI0) + mi_) * 2048); \
    }

#define READ_B(BUF, NI0, DST)                                                   \
    _Pragma("unroll")                                                           \
    for (int ni_ = 0; ni_ < 2; ++ni_) {                                         \
        DST[2 * ni_]     = *(const i32x4*)((BUF) + offB_k0 + ((NI0) + ni_) * 2048); \
        DST[2 * ni_ + 1] = *(const i32x4*)((BUF) + offB_k1 + ((NI0) + ni_) * 2048); \
    }

#define MFMA_Q(MI0, NI0, BSRC)                                                  \
    do {                                                                        \
        __builtin_amdgcn_s_setprio(1);                                          \
        _Pragma("unroll")                                                       \
        for (int mi_ = 0; mi_ < 4; ++mi_) {                                     \
            _Pragma("unroll")                                                   \
            for (int ni_ = 0; ni_ < 2; ++ni_) {                                 \
                acc[(MI0) + mi_][(NI0) + ni_] =                                 \
                    __builtin_amdgcn_mfma_i32_16x16x64_i8(                      \
                        a[2 * mi_], BSRC[2 * ni_],                              \
                        acc[(MI0) + mi_][(NI0) + ni_], 0, 0, 0);                \
                acc[(MI0) + mi_][(NI0) + ni_] =                                 \
                    __builtin_amdgcn_mfma_i32_16x16x64_i8(                      \
                        a[2 * mi_ + 1], BSRC[2 * ni_ + 1],                      \
                        acc[(MI0) + mi_][(NI0) + ni_], 0, 0, 0);                \
            }                                                                   \
        }                                                                       \
        __builtin_amdgcn_s_setprio(0);                                          \
    } while (0)

__global__ __launch_bounds__(512, 2) void gemm_i8_8ph(
    const int8_t* __restrict__ Xq,   // [M,K]
    const int8_t* __restrict__ Tq,   // [N,K]
    const float* __restrict__ bias,  // [N]
    float* __restrict__ out) {
    extern __shared__ __align__(16) int8_t lds[];  // 131072 B
    const int K = IN_F;
    const int NT = K / 128;   // 32 K-tiles
    const int NI = NT / 2;    // 16 iterations

    const int t = threadIdx.x;
    const int lane = t & 63;
    const int wave = t >> 6;
    const int lm = lane & 15;
    const int qh = lane >> 4;
    const int wm = (wave >> 2) << 7;
    const int wn = (wave & 3) << 6;

    const int nwg = gridDim.x;
    const int id = blockIdx.x;
    const int swz = (id & 7) * (nwg >> 3) + (id >> 3);
    const int m0 = (swz >> 4) << 8;
    const int n0 = (swz & 15) << 8;

    int8_t* const A0  = lds;
    int8_t* const B0  = lds + 32768;
    int8_t* const A1b = lds + 65536;
    int8_t* const B1b = lds + 98304;

    const int swzs = lm & 7;
    const int offA_k0 = (wm + lm) * 128 + ((qh ^ swzs) << 4);
    const int offA_k1 = (wm + lm) * 128 + (((4 + qh) ^ swzs) << 4);
    const int offB_k0 = (wn + lm) * 128 + ((qh ^ swzs) << 4);
    const int offB_k1 = (wn + lm) * 128 + (((4 + qh) ^ swzs) << 4);

    i32x4 acc[8][4];
#pragma unroll
    for (int i = 0; i < 8; ++i)
#pragma unroll
        for (int j = 0; j < 4; ++j)
#pragma unroll
            for (int r = 0; r < 4; ++r) acc[i][j][r] = 0;

    i32x4 a[8], bA[4], bB[4];

    // ---- prologue: A(0),B(0)->buf0, B(1)->B1; leave B(1)'s 4 in flight
    STAGE(Xq, m0, 0, A0, 0);
    STAGE(Xq, m0, 0, A0, 1);
    STAGE(Tq, n0, 0, B0, 0);
    STAGE(Tq, n0, 0, B0, 1);
    STAGE(Tq, n0, 1, B1b, 0);
    STAGE(Tq, n0, 1, B1b, 1);
    asm volatile("s_waitcnt vmcnt(4)" ::: "memory");
    GBARRIER();

#pragma unroll 1
    for (int i = 0; i < NI; ++i) {
        const int kt = 2 * i;
        // -- phase 0: buf0 A-lo + B all; stage A(kt+1)->A1
        READ_A(A0, 0);
        READ_B(B0, 0, bA);
        READ_B(B0, 2, bB);
        STAGE(Xq, m0, kt + 1, A1b, 0);
        STAGE(Xq, m0, kt + 1, A1b, 1);
        MFMA_Q(0, 0, bA);
        MFMA_Q(0, 2, bB);
        GBARRIER();
        // -- phase 1: buf0 A-hi; stage B(kt+2)->B0; wait A1,B1 ready
        READ_A(A0, 4);
        if (kt + 2 < NT) {
            STAGE(Tq, n0, kt + 2, B0, 0);
            STAGE(Tq, n0, kt + 2, B0, 1);
        }
        MFMA_Q(4, 0, bA);
        MFMA_Q(4, 2, bB);
        if (i + 1 < NI) asm volatile("s_waitcnt vmcnt(4)" ::: "memory");
        else            asm volatile("s_waitcnt vmcnt(0)" ::: "memory");
        GBARRIER();
        // -- phase 2: buf1 A-lo + B all; stage A(kt+2)->A0
        READ_A(A1b, 0);
        READ_B(B1b, 0, bA);
        READ_B(B1b, 2, bB);
        if (kt + 2 < NT) {
            STAGE(Xq, m0, kt + 2, A0, 0);
            STAGE(Xq, m0, kt + 2, A0, 1);
        }
        MFMA_Q(0, 0, bA);
        MFMA_Q(0, 2, bB);
        GBARRIER();
        // -- phase 3: buf1 A-hi; stage B(kt+3)->B1; wait A0,B0 ready
        READ_A(A1b, 4);
        if (kt + 3 < NT) {
            STAGE(Tq, n0, kt + 3, B1b, 0);
            STAGE(Tq, n0, kt + 3, B1b, 1);
        }
        MFMA_Q(4, 0, bA);
        MFMA_Q(4, 2, bB);
        if (i + 1 < NI) asm volatile("s_waitcnt vmcnt(4)" ::: "memory");
        else            asm volatile("s_waitcnt vmcnt(0)" ::: "memory");
        GBARRIER();
    }

    // ---- epilogue: C/D layout col=lane&15, row=(lane>>4)*4+reg
    const int q4 = qh << 2;
#pragma unroll
    for (int mi = 0; mi < 8; ++mi) {
        float sc[4];
#pragma unroll
        for (int r = 0; r < 4; ++r) sc[r] = g_scale[m0 + wm + mi * 16 + q4 + r];
#pragma unroll
        for (int ni = 0; ni < 4; ++ni) {
            int col = n0 + wn + ni * 16 + lm;
            float b = bias[col];
#pragma unroll
            for (int r = 0; r < 4; ++r) {
                int row = m0 + wm + mi * 16 + q4 + r;
                out[(size_t)row * OUT_F + col] =
                    (float)acc[mi][ni][r] * sc[r] + b;
            }
        }
    }
}

// ---------- launch ----------

extern "C" void kernel_launch(void* const* d_in, const int* in_sizes, int n_in,
                              void* d_out, int out_size, void* d_ws, size_t ws_size,
                              hipStream_t stream) {
    const float* x = (const float*)d_in[0];
    const float* w = (const float*)d_in[1];
    const float* bias = (const float*)d_in[2];
    float* out = (float*)d_out;
    const int B = in_sizes[0] / IN_F;  // 8192

    // ws layout (48 MB):
    //   [0, 16M)    Tt [OUT][IN] i8
    //   [16M, 48M)  Xq [B][IN] i8
    // alpha/delta/scale live in __device__ globals (no aliasing).
    char* ws = (char*)d_ws;
    int8_t* Tt = (int8_t*)ws;
    int8_t* Xq = (int8_t*)(ws + (size_t)16777216);

    static int lds_set = 0;
    if (!lds_set) {
        hipFuncSetAttribute((const void*)gemm_i8_8ph,
                            hipFuncAttributeMaxDynamicSharedMemorySize, 131072);
        lds_set = 1;
    }

    rowstats_kernel<<<IN_F, 256, 0, stream>>>(w);
    fused_tq<<<B + (IN_F / 128) * (OUT_F / 128), 256, 0, stream>>>(w, x, Xq, Tt, B);
    const int nwg = (B / 256) * (OUT_F / 256);  // 512
    gemm_i8_8ph<<<dim3(nwg), dim3(512), 131072, stream>>>(Xq, Tt, bias, out);
}